// Round 5
// baseline (566.723 us; speedup 1.0000x reference)
//
#include <hip/hip_runtime.h>

#define N_USERS 100000
#define N_ITEMS 50000
#define N_NODES 150000
#define NNZ_EDGES 4000000
#define BATCH_SZ 16384
#define DIM 64
#define ALPHA 0.1f
#define BETA 0.9f          // 1 - ALPHA
#define SCAN_B 1024
#define N_SCAN_BLOCKS ((N_NODES + SCAN_B - 1) / SCAN_B)   // 147
#define R_REP 16           // histogram replicas (atomic-contention spread)

// ---------- CSR build ----------
// Pass A: replicated histogram + per-edge rank. Block b uses replica b&15,
// so concurrent atomics to one logical counter spread over 16 cache lines.
__global__ void gtn_hist_rank_kernel(const int* __restrict__ row,
                                     int* __restrict__ repCnt,
                                     int* __restrict__ rank) {
    const int e = blockIdx.x * blockDim.x + threadIdx.x;
    if (e >= NNZ_EDGES) return;
    const int rep = blockIdx.x & (R_REP - 1);
    rank[e] = atomicAdd(&repCnt[rep * N_NODES + row[e]], 1);
}

// Per node: replica counts -> exclusive per-replica bases (in place) + total.
__global__ void gtn_repscan_kernel(int* __restrict__ repCnt,
                                   int* __restrict__ cnt) {
    const int n = blockIdx.x * blockDim.x + threadIdx.x;
    if (n >= N_NODES) return;
    int acc = 0;
#pragma unroll
    for (int r = 0; r < R_REP; ++r) {
        const int v = repCnt[r * N_NODES + n];
        repCnt[r * N_NODES + n] = acc;
        acc += v;
    }
    cnt[n] = acc;
}

// block-local exclusive scan of cnt -> rowPtr, block sums -> bsum
__global__ void gtn_scan1_kernel(const int* __restrict__ cnt,
                                 int* __restrict__ rowPtr,
                                 int* __restrict__ bsum) {
    __shared__ int s[SCAN_B];
    const int i = blockIdx.x * SCAN_B + threadIdx.x;
    const int v = (i < N_NODES) ? cnt[i] : 0;
    s[threadIdx.x] = v;
    __syncthreads();
    for (int off = 1; off < SCAN_B; off <<= 1) {
        int t = (threadIdx.x >= off) ? s[threadIdx.x - off] : 0;
        __syncthreads();
        s[threadIdx.x] += t;
        __syncthreads();
    }
    if (i < N_NODES) rowPtr[i] = s[threadIdx.x] - v;   // exclusive within block
    if (threadIdx.x == SCAN_B - 1) bsum[blockIdx.x] = s[SCAN_B - 1];
}

// serial exclusive scan of 147 block sums (trivial)
__global__ void gtn_scan2_kernel(int* __restrict__ bsum) {
    int acc = 0;
    for (int i = 0; i < N_SCAN_BLOCKS; ++i) { int v = bsum[i]; bsum[i] = acc; acc += v; }
}

__global__ void gtn_scan3_kernel(int* __restrict__ rowPtr,
                                 const int* __restrict__ bsum) {
    const int i = blockIdx.x * SCAN_B + threadIdx.x;
    if (i < N_NODES) rowPtr[i] += bsum[blockIdx.x];
}

// Fold rowPtr into the replica bases: afterwards repCnt[r][n] is the absolute
// destination base for (replica r, node n) -> fill needs ONE random read.
__global__ void gtn_addbase_kernel(int* __restrict__ repCnt,
                                   const int* __restrict__ rowPtr) {
    const int n = blockIdx.x * blockDim.x + threadIdx.x;
    if (n >= N_NODES) return;
    const int base = rowPtr[n];
#pragma unroll
    for (int r = 0; r < R_REP; ++r) repCnt[r * N_NODES + n] += base;
}

// Pass B: atomic-free scatter. Every thread's store is independent -> full MLP.
__global__ void gtn_fill_kernel(const int* __restrict__ row,
                                const int* __restrict__ col,
                                const float* __restrict__ w,
                                const int* __restrict__ rank,
                                const int* __restrict__ repCnt,
                                int2* __restrict__ colw) {
    const int e = blockIdx.x * blockDim.x + threadIdx.x;
    if (e >= NNZ_EDGES) return;
    const int rep = blockIdx.x & (R_REP - 1);
    const int pos = repCnt[rep * N_NODES + row[e]] + rank[e];
    colw[pos] = make_int2(col[e], __float_as_int(w[e]));
}

// ---------- gather (vectorized: 16 lanes x float4 per edge, 4 edges/wave) ----
// lane = grp*16 + sub. Group g handles edges 4j+g; each lane holds dims
// [4*sub, 4*sub+4) as a float4 partial accumulator. Invalid tail lanes carry
// (c=0, w=0) so the FMA is a harmless no-op against row 0 (branch-free).
__device__ __forceinline__ float4 gtn_gather_row_v4(
        int node, int lane, int sub, int grp,
        const float* __restrict__ xu, const float* __restrict__ xi,
        const int* __restrict__ rowPtr, const int* __restrict__ cnt,
        const int2* __restrict__ colw) {
    const int start = rowPtr[node];
    const int n = cnt[node];
    float4 acc = make_float4(0.f, 0.f, 0.f, 0.f);
    for (int base = 0; base < n; base += 64) {
        const int m = min(64, n - base);
        int2 e = make_int2(0, 0);
        if (lane < m) e = colw[start + base + lane];
        const int nj = (m + 3) >> 2;
        for (int j = 0; j < nj; ++j) {
            const int src = (j << 2) + grp;           // src <= 63 always
            const int c = __shfl(e.x, src, 64);
            const float wv = __int_as_float(__shfl(e.y, src, 64));
            const float4* xp = (c < N_USERS)
                ? (const float4*)(xu + (size_t)c * DIM)
                : (const float4*)(xi + (size_t)(c - N_USERS) * DIM);
            const float4 xv = xp[sub];
            acc.x = fmaf(wv, xv.x, acc.x);
            acc.y = fmaf(wv, xv.y, acc.y);
            acc.z = fmaf(wv, xv.z, acc.z);
            acc.w = fmaf(wv, xv.w, acc.w);
        }
    }
    return acc;
}

// butterfly-sum the 4 group partials; afterwards ALL lanes hold the full sum
__device__ __forceinline__ float4 gtn_reduce_groups(float4 a) {
    a.x += __shfl_xor(a.x, 16, 64);
    a.y += __shfl_xor(a.y, 16, 64);
    a.z += __shfl_xor(a.z, 16, 64);
    a.w += __shfl_xor(a.w, 16, 64);
    a.x += __shfl_xor(a.x, 32, 64);
    a.y += __shfl_xor(a.y, 32, 64);
    a.z += __shfl_xor(a.z, 32, 64);
    a.w += __shfl_xor(a.w, 32, 64);
    return a;
}

// out[node] = ALPHA * x0[node] + BETA * gather(node); one wave per node
__global__ void gtn_layer_kernel(const float* __restrict__ xu,
                                 const float* __restrict__ xi,
                                 const float* __restrict__ x0u,
                                 const float* __restrict__ x0i,
                                 const int* __restrict__ rowPtr,
                                 const int* __restrict__ cnt,
                                 const int2* __restrict__ colw,
                                 float* __restrict__ out) {
    const int lane = threadIdx.x & 63;
    const int sub = lane & 15;
    const int grp = lane >> 4;
    const int node = (blockIdx.x * blockDim.x + threadIdx.x) >> 6;
    if (node >= N_NODES) return;
    float4 agg = gtn_gather_row_v4(node, lane, sub, grp, xu, xi, rowPtr, cnt, colw);
    agg = gtn_reduce_groups(agg);
    if (grp == 0) {
        const float4 x0v = (node < N_USERS)
            ? ((const float4*)(x0u + (size_t)node * DIM))[sub]
            : ((const float4*)(x0i + (size_t)(node - N_USERS) * DIM))[sub];
        float4 o;
        o.x = ALPHA * x0v.x + BETA * agg.x;
        o.y = ALPHA * x0v.y + BETA * agg.y;
        o.z = ALPHA * x0v.z + BETA * agg.z;
        o.w = ALPHA * x0v.w + BETA * agg.w;
        ((float4*)(out + (size_t)node * DIM))[sub] = o;
    }
}

// Fused layer-3 + dot: only the 2*BATCH needed rows of x3 are ever computed.
__global__ void gtn_l3_dot_kernel(const float* __restrict__ xu,   // bufB user part
                                  const float* __restrict__ xi,   // bufB item part
                                  const float* __restrict__ x0u,
                                  const float* __restrict__ x0i,
                                  const int* __restrict__ rowPtr,
                                  const int* __restrict__ cnt,
                                  const int2* __restrict__ colw,
                                  const int* __restrict__ users,
                                  const int* __restrict__ items,
                                  float* __restrict__ out) {
    const int lane = threadIdx.x & 63;
    const int sub = lane & 15;
    const int grp = lane >> 4;
    const int b = (blockIdx.x * blockDim.x + threadIdx.x) >> 6;
    if (b >= BATCH_SZ) return;
    const int u = users[b];
    const int it = items[b] + N_USERS;

    float4 au = gtn_gather_row_v4(u, lane, sub, grp, xu, xi, rowPtr, cnt, colw);
    au = gtn_reduce_groups(au);
    float4 ai = gtn_gather_row_v4(it, lane, sub, grp, xu, xi, rowPtr, cnt, colw);
    ai = gtn_reduce_groups(ai);

    const float4 x0uv = ((const float4*)(x0u + (size_t)u * DIM))[sub];
    const float4 x0iv = ((const float4*)(x0i + (size_t)(it - N_USERS) * DIM))[sub];
    float4 vu, vi;
    vu.x = ALPHA * x0uv.x + BETA * au.x;  vi.x = ALPHA * x0iv.x + BETA * ai.x;
    vu.y = ALPHA * x0uv.y + BETA * au.y;  vi.y = ALPHA * x0iv.y + BETA * ai.y;
    vu.z = ALPHA * x0uv.z + BETA * au.z;  vi.z = ALPHA * x0iv.z + BETA * ai.z;
    vu.w = ALPHA * x0uv.w + BETA * au.w;  vi.w = ALPHA * x0iv.w + BETA * ai.w;

    float p = vu.x * vi.x + vu.y * vi.y + vu.z * vi.z + vu.w * vi.w;
    // reduce over the 16 subs (all 4 groups hold identical values)
    p += __shfl_xor(p, 1, 64);
    p += __shfl_xor(p, 2, 64);
    p += __shfl_xor(p, 4, 64);
    p += __shfl_xor(p, 8, 64);
    if (lane == 0) out[b] = p;
}

extern "C" void kernel_launch(void* const* d_in, const int* in_sizes, int n_in,
                              void* d_out, int out_size, void* d_ws, size_t ws_size,
                              hipStream_t stream) {
    const float* user_emb  = (const float*)d_in[0];
    const float* item_emb  = (const float*)d_in[1];
    const float* edge_vals = (const float*)d_in[2];
    const int*   row       = (const int*)d_in[3];
    const int*   col       = (const int*)d_in[4];
    const int*   users     = (const int*)d_in[5];
    const int*   items     = (const int*)d_in[6];
    float* out = (float*)d_out;

    // workspace layout
    char* p = (char*)d_ws;
    float* bufA   = (float*)p;  p += (size_t)N_NODES * DIM * sizeof(float);   // 38.4 MB
    float* bufB   = (float*)p;  p += (size_t)N_NODES * DIM * sizeof(float);   // 38.4 MB
    int2*  colw   = (int2*)p;   p += (size_t)NNZ_EDGES * sizeof(int2);        // 32 MB
    int*   rank   = (int*)p;    p += (size_t)NNZ_EDGES * sizeof(int);         // 16 MB
    int*   repCnt = (int*)p;    p += (size_t)R_REP * N_NODES * sizeof(int);   // 9.6 MB
    int*   cnt    = (int*)p;    p += (size_t)N_NODES * sizeof(int);
    int*   rowPtr = (int*)p;    p += (size_t)N_NODES * sizeof(int);
    int*   bsum   = (int*)p;    p += 256 * sizeof(int);

    const dim3 blk(256);
    const dim3 edgeGrid((NNZ_EDGES + 255) / 256);       // 15625 blocks, 1 edge/thread
    const dim3 nodeGrid((N_NODES + 255) / 256);         // 586 blocks

    // ---- CSR build ----
    hipMemsetAsync(repCnt, 0, (size_t)R_REP * N_NODES * sizeof(int), stream);
    gtn_hist_rank_kernel<<<edgeGrid, blk, 0, stream>>>(row, repCnt, rank);
    gtn_repscan_kernel<<<nodeGrid, blk, 0, stream>>>(repCnt, cnt);
    gtn_scan1_kernel<<<dim3(N_SCAN_BLOCKS), dim3(SCAN_B), 0, stream>>>(cnt, rowPtr, bsum);
    gtn_scan2_kernel<<<dim3(1), dim3(1), 0, stream>>>(bsum);
    gtn_scan3_kernel<<<dim3(N_SCAN_BLOCKS), dim3(SCAN_B), 0, stream>>>(rowPtr, bsum);
    gtn_addbase_kernel<<<nodeGrid, blk, 0, stream>>>(repCnt, rowPtr);
    gtn_fill_kernel<<<edgeGrid, blk, 0, stream>>>(row, col, edge_vals, rank, repCnt, colw);

    // ---- layers (gather, one wave per node) ----
    const dim3 layerGrid((N_NODES * 64 + 255) / 256);   // 37500 blocks
    // L1: bufA = f(x0), x0 read directly from inputs
    gtn_layer_kernel<<<layerGrid, blk, 0, stream>>>(
        user_emb, item_emb, user_emb, item_emb, rowPtr, cnt, colw, bufA);
    // L2: bufB = f(bufA)
    gtn_layer_kernel<<<layerGrid, blk, 0, stream>>>(
        bufA, bufA + (size_t)N_USERS * DIM, user_emb, item_emb, rowPtr, cnt, colw, bufB);
    // L3 + dot fused, only at batch nodes
    const dim3 dotGrid((BATCH_SZ * 64) / 256);          // 4096 blocks
    gtn_l3_dot_kernel<<<dotGrid, blk, 0, stream>>>(
        bufB, bufB + (size_t)N_USERS * DIM, user_emb, item_emb,
        rowPtr, cnt, colw, users, items, out);
}

// Round 6
// 495.399 us; speedup vs baseline: 1.1440x; 1.1440x over previous
//
#include <hip/hip_runtime.h>

#define N_USERS 100000
#define N_ITEMS 50000
#define N_NODES 150000
#define NNZ_EDGES 4000000
#define BATCH_SZ 16384
#define DIM 64
#define ALPHA 0.1f
#define BETA 0.9f          // 1 - ALPHA
#define SCAN_B 1024
#define N_SCAN_BLOCKS ((N_NODES + SCAN_B - 1) / SCAN_B)   // 147

// ---------- bf16 helpers (storage-only precision; accumulate in fp32) ------
__device__ __forceinline__ float gtn_bf2f(unsigned short h) {
    return __uint_as_float(((unsigned int)h) << 16);
}
__device__ __forceinline__ unsigned short gtn_f2bf(float f) {
    unsigned int u = __float_as_uint(f);
    u = u + 0x7FFFu + ((u >> 16) & 1u);      // round-to-nearest-even
    return (unsigned short)(u >> 16);
}

// ---------- CSR build ----------
// Pass A: histogram + per-edge rank (atomic result feeds only a coalesced
// store). Known wall: ~24G scattered returning atomics/s (fabric RMW limit).
__global__ void gtn_hist_rank_kernel(const int* __restrict__ row,
                                     int* __restrict__ cnt,
                                     int* __restrict__ rank) {
    const int e = blockIdx.x * blockDim.x + threadIdx.x;
    if (e < NNZ_EDGES) rank[e] = atomicAdd(&cnt[row[e]], 1);
}

// block-local exclusive scan of cnt -> rowPtr, block sums -> bsum
__global__ void gtn_scan1_kernel(const int* __restrict__ cnt,
                                 int* __restrict__ rowPtr,
                                 int* __restrict__ bsum) {
    __shared__ int s[SCAN_B];
    const int i = blockIdx.x * SCAN_B + threadIdx.x;
    const int v = (i < N_NODES) ? cnt[i] : 0;
    s[threadIdx.x] = v;
    __syncthreads();
    for (int off = 1; off < SCAN_B; off <<= 1) {
        int t = (threadIdx.x >= off) ? s[threadIdx.x - off] : 0;
        __syncthreads();
        s[threadIdx.x] += t;
        __syncthreads();
    }
    if (i < N_NODES) rowPtr[i] = s[threadIdx.x] - v;   // exclusive within block
    if (threadIdx.x == SCAN_B - 1) bsum[blockIdx.x] = s[SCAN_B - 1];
}

// serial exclusive scan of 147 block sums (trivial)
__global__ void gtn_scan2_kernel(int* __restrict__ bsum) {
    int acc = 0;
    for (int i = 0; i < N_SCAN_BLOCKS; ++i) { int v = bsum[i]; bsum[i] = acc; acc += v; }
}

__global__ void gtn_scan3_kernel(int* __restrict__ rowPtr,
                                 const int* __restrict__ bsum) {
    const int i = blockIdx.x * SCAN_B + threadIdx.x;
    if (i < N_NODES) rowPtr[i] += bsum[blockIdx.x];
}

// Pass B: atomic-free scatter. Every thread's store is independent -> full MLP.
__global__ void gtn_fill_kernel(const int* __restrict__ row,
                                const int* __restrict__ col,
                                const float* __restrict__ w,
                                const int* __restrict__ rank,
                                const int* __restrict__ rowPtr,
                                int2* __restrict__ colw) {
    const int e = blockIdx.x * blockDim.x + threadIdx.x;
    if (e >= NNZ_EDGES) return;
    const int pos = rowPtr[row[e]] + rank[e];
    colw[pos] = make_int2(col[e], __float_as_int(w[e]));
}

// ---------- gather (16 lanes x 4 dims per edge, 4 edges/wave) ----------
// lane = grp*16 + sub. Group g handles edges 4j+g; lane holds dims
// [4*sub, 4*sub+4) as fp32 partial accumulators. Tail lanes carry (c=0,w=0)
// so the FMA is a harmless no-op against row 0 (branch-free).

// fp32 source (layer 1: reads the original split input embeddings)
__device__ __forceinline__ float4 gtn_gather_row_f32(
        int node, int lane, int sub, int grp,
        const float* __restrict__ xu, const float* __restrict__ xi,
        const int* __restrict__ rowPtr, const int* __restrict__ cnt,
        const int2* __restrict__ colw) {
    const int start = rowPtr[node];
    const int n = cnt[node];
    float4 acc = make_float4(0.f, 0.f, 0.f, 0.f);
    for (int base = 0; base < n; base += 64) {
        const int m = min(64, n - base);
        int2 e = make_int2(0, 0);
        if (lane < m) e = colw[start + base + lane];
        const int nj = (m + 3) >> 2;
        for (int j = 0; j < nj; ++j) {
            const int src = (j << 2) + grp;
            const int c = __shfl(e.x, src, 64);
            const float wv = __int_as_float(__shfl(e.y, src, 64));
            const float4* xp = (c < N_USERS)
                ? (const float4*)(xu + (size_t)c * DIM)
                : (const float4*)(xi + (size_t)(c - N_USERS) * DIM);
            const float4 xv = xp[sub];
            acc.x = fmaf(wv, xv.x, acc.x);
            acc.y = fmaf(wv, xv.y, acc.y);
            acc.z = fmaf(wv, xv.z, acc.z);
            acc.w = fmaf(wv, xv.w, acc.w);
        }
    }
    return acc;
}

// bf16 source (layers 2/3: reads the bf16 ping-pong buffer, contiguous rows)
__device__ __forceinline__ float4 gtn_gather_row_bf16(
        int node, int lane, int sub, int grp,
        const unsigned short* __restrict__ x,
        const int* __restrict__ rowPtr, const int* __restrict__ cnt,
        const int2* __restrict__ colw) {
    const int start = rowPtr[node];
    const int n = cnt[node];
    float4 acc = make_float4(0.f, 0.f, 0.f, 0.f);
    for (int base = 0; base < n; base += 64) {
        const int m = min(64, n - base);
        int2 e = make_int2(0, 0);
        if (lane < m) e = colw[start + base + lane];
        const int nj = (m + 3) >> 2;
        for (int j = 0; j < nj; ++j) {
            const int src = (j << 2) + grp;
            const int c = __shfl(e.x, src, 64);
            const float wv = __int_as_float(__shfl(e.y, src, 64));
            const ushort4 xv = *(const ushort4*)(x + (size_t)c * DIM + (sub << 2));
            acc.x = fmaf(wv, gtn_bf2f(xv.x), acc.x);
            acc.y = fmaf(wv, gtn_bf2f(xv.y), acc.y);
            acc.z = fmaf(wv, gtn_bf2f(xv.z), acc.z);
            acc.w = fmaf(wv, gtn_bf2f(xv.w), acc.w);
        }
    }
    return acc;
}

// butterfly-sum the 4 group partials; afterwards ALL lanes hold the full sum
__device__ __forceinline__ float4 gtn_reduce_groups(float4 a) {
    a.x += __shfl_xor(a.x, 16, 64);
    a.y += __shfl_xor(a.y, 16, 64);
    a.z += __shfl_xor(a.z, 16, 64);
    a.w += __shfl_xor(a.w, 16, 64);
    a.x += __shfl_xor(a.x, 32, 64);
    a.y += __shfl_xor(a.y, 32, 64);
    a.z += __shfl_xor(a.z, 32, 64);
    a.w += __shfl_xor(a.w, 32, 64);
    return a;
}

__device__ __forceinline__ void gtn_store_bf16_row(unsigned short* out,
                                                   int node, int sub, float4 o) {
    ushort4 o4;
    o4.x = gtn_f2bf(o.x);
    o4.y = gtn_f2bf(o.y);
    o4.z = gtn_f2bf(o.z);
    o4.w = gtn_f2bf(o.w);
    ((ushort4*)(out + (size_t)node * DIM))[sub] = o4;
}

// Layer 1: out(bf16) = ALPHA*x0 + BETA*gather(x0) with x0 = fp32 inputs
__global__ void gtn_layer1_kernel(const float* __restrict__ xu,
                                  const float* __restrict__ xi,
                                  const int* __restrict__ rowPtr,
                                  const int* __restrict__ cnt,
                                  const int2* __restrict__ colw,
                                  unsigned short* __restrict__ out) {
    const int lane = threadIdx.x & 63;
    const int sub = lane & 15;
    const int grp = lane >> 4;
    const int node = (blockIdx.x * blockDim.x + threadIdx.x) >> 6;
    if (node >= N_NODES) return;
    float4 agg = gtn_gather_row_f32(node, lane, sub, grp, xu, xi, rowPtr, cnt, colw);
    agg = gtn_reduce_groups(agg);
    if (grp == 0) {
        const float4 x0v = (node < N_USERS)
            ? ((const float4*)(xu + (size_t)node * DIM))[sub]
            : ((const float4*)(xi + (size_t)(node - N_USERS) * DIM))[sub];
        float4 o;
        o.x = ALPHA * x0v.x + BETA * agg.x;
        o.y = ALPHA * x0v.y + BETA * agg.y;
        o.z = ALPHA * x0v.z + BETA * agg.z;
        o.w = ALPHA * x0v.w + BETA * agg.w;
        gtn_store_bf16_row(out, node, sub, o);
    }
}

// Layer 2: out(bf16) = ALPHA*x0(fp32 inputs) + BETA*gather(bf16 buf)
__global__ void gtn_layer2_kernel(const unsigned short* __restrict__ x,
                                  const float* __restrict__ x0u,
                                  const float* __restrict__ x0i,
                                  const int* __restrict__ rowPtr,
                                  const int* __restrict__ cnt,
                                  const int2* __restrict__ colw,
                                  unsigned short* __restrict__ out) {
    const int lane = threadIdx.x & 63;
    const int sub = lane & 15;
    const int grp = lane >> 4;
    const int node = (blockIdx.x * blockDim.x + threadIdx.x) >> 6;
    if (node >= N_NODES) return;
    float4 agg = gtn_gather_row_bf16(node, lane, sub, grp, x, rowPtr, cnt, colw);
    agg = gtn_reduce_groups(agg);
    if (grp == 0) {
        const float4 x0v = (node < N_USERS)
            ? ((const float4*)(x0u + (size_t)node * DIM))[sub]
            : ((const float4*)(x0i + (size_t)(node - N_USERS) * DIM))[sub];
        float4 o;
        o.x = ALPHA * x0v.x + BETA * agg.x;
        o.y = ALPHA * x0v.y + BETA * agg.y;
        o.z = ALPHA * x0v.z + BETA * agg.z;
        o.w = ALPHA * x0v.w + BETA * agg.w;
        gtn_store_bf16_row(out, node, sub, o);
    }
}

// Fused layer-3 + dot at batch nodes only (gathers from bf16 buf)
__global__ void gtn_l3_dot_kernel(const unsigned short* __restrict__ x,
                                  const float* __restrict__ x0u,
                                  const float* __restrict__ x0i,
                                  const int* __restrict__ rowPtr,
                                  const int* __restrict__ cnt,
                                  const int2* __restrict__ colw,
                                  const int* __restrict__ users,
                                  const int* __restrict__ items,
                                  float* __restrict__ out) {
    const int lane = threadIdx.x & 63;
    const int sub = lane & 15;
    const int grp = lane >> 4;
    const int b = (blockIdx.x * blockDim.x + threadIdx.x) >> 6;
    if (b >= BATCH_SZ) return;
    const int u = users[b];
    const int it = items[b] + N_USERS;

    float4 au = gtn_gather_row_bf16(u, lane, sub, grp, x, rowPtr, cnt, colw);
    au = gtn_reduce_groups(au);
    float4 ai = gtn_gather_row_bf16(it, lane, sub, grp, x, rowPtr, cnt, colw);
    ai = gtn_reduce_groups(ai);

    const float4 x0uv = ((const float4*)(x0u + (size_t)u * DIM))[sub];
    const float4 x0iv = ((const float4*)(x0i + (size_t)(it - N_USERS) * DIM))[sub];
    float4 vu, vi;
    vu.x = ALPHA * x0uv.x + BETA * au.x;  vi.x = ALPHA * x0iv.x + BETA * ai.x;
    vu.y = ALPHA * x0uv.y + BETA * au.y;  vi.y = ALPHA * x0iv.y + BETA * ai.y;
    vu.z = ALPHA * x0uv.z + BETA * au.z;  vi.z = ALPHA * x0iv.z + BETA * ai.z;
    vu.w = ALPHA * x0uv.w + BETA * au.w;  vi.w = ALPHA * x0iv.w + BETA * ai.w;

    float p = vu.x * vi.x + vu.y * vi.y + vu.z * vi.z + vu.w * vi.w;
    p += __shfl_xor(p, 1, 64);
    p += __shfl_xor(p, 2, 64);
    p += __shfl_xor(p, 4, 64);
    p += __shfl_xor(p, 8, 64);
    if (lane == 0) out[b] = p;
}

extern "C" void kernel_launch(void* const* d_in, const int* in_sizes, int n_in,
                              void* d_out, int out_size, void* d_ws, size_t ws_size,
                              hipStream_t stream) {
    const float* user_emb  = (const float*)d_in[0];
    const float* item_emb  = (const float*)d_in[1];
    const float* edge_vals = (const float*)d_in[2];
    const int*   row       = (const int*)d_in[3];
    const int*   col       = (const int*)d_in[4];
    const int*   users     = (const int*)d_in[5];
    const int*   items     = (const int*)d_in[6];
    float* out = (float*)d_out;

    // workspace layout
    char* p = (char*)d_ws;
    unsigned short* bufA = (unsigned short*)p; p += (size_t)N_NODES * DIM * 2; // 19.2 MB
    unsigned short* bufB = (unsigned short*)p; p += (size_t)N_NODES * DIM * 2; // 19.2 MB
    int2*  colw   = (int2*)p;   p += (size_t)NNZ_EDGES * sizeof(int2);         // 32 MB
    int*   rank   = (int*)p;    p += (size_t)NNZ_EDGES * sizeof(int);          // 16 MB
    int*   cnt    = (int*)p;    p += (size_t)N_NODES * sizeof(int);
    int*   rowPtr = (int*)p;    p += (size_t)N_NODES * sizeof(int);
    int*   bsum   = (int*)p;    p += 256 * sizeof(int);

    const dim3 blk(256);
    const dim3 edgeGrid((NNZ_EDGES + 255) / 256);       // 15625 blocks, 1 edge/thread

    // ---- CSR build ----
    hipMemsetAsync(cnt, 0, (size_t)N_NODES * sizeof(int), stream);
    gtn_hist_rank_kernel<<<edgeGrid, blk, 0, stream>>>(row, cnt, rank);
    gtn_scan1_kernel<<<dim3(N_SCAN_BLOCKS), dim3(SCAN_B), 0, stream>>>(cnt, rowPtr, bsum);
    gtn_scan2_kernel<<<dim3(1), dim3(1), 0, stream>>>(bsum);
    gtn_scan3_kernel<<<dim3(N_SCAN_BLOCKS), dim3(SCAN_B), 0, stream>>>(rowPtr, bsum);
    gtn_fill_kernel<<<edgeGrid, blk, 0, stream>>>(row, col, edge_vals, rank, rowPtr, colw);

    // ---- layers (gather, one wave per node) ----
    const dim3 layerGrid((N_NODES * 64 + 255) / 256);   // 37500 blocks
    gtn_layer1_kernel<<<layerGrid, blk, 0, stream>>>(
        user_emb, item_emb, rowPtr, cnt, colw, bufA);
    gtn_layer2_kernel<<<layerGrid, blk, 0, stream>>>(
        bufA, user_emb, item_emb, rowPtr, cnt, colw, bufB);
    const dim3 dotGrid((BATCH_SZ * 64) / 256);          // 4096 blocks
    gtn_l3_dot_kernel<<<dotGrid, blk, 0, stream>>>(
        bufB, user_emb, item_emb, rowPtr, cnt, colw, users, items, out);
}

// Round 7
// 395.935 us; speedup vs baseline: 1.4314x; 1.2512x over previous
//
#include <hip/hip_runtime.h>

#define N_USERS 100000
#define N_ITEMS 50000
#define N_NODES 150000
#define NNZ_EDGES 4000000
#define BATCH_SZ 16384
#define DIM 64
#define ALPHA 0.1f
#define BETA 0.9f          // 1 - ALPHA
#define SCAN_B 1024
#define N_SCAN_BLOCKS ((N_NODES + SCAN_B - 1) / SCAN_B)   // 147

#define BKT_SHIFT 9
#define BKT_ROWS  (1 << BKT_SHIFT)                        // 512 rows per bucket
#define NBKT      ((N_NODES + BKT_ROWS - 1) >> BKT_SHIFT) // 293
#define BKT_CAP   16384            // mean 13651, sigma ~117 -> 23 sigma headroom
#define BKT_PAD   16               // bucketCnt stride (64B) -> own cache line
#define BIN_CHUNK 32768            // edges per bin-scatter block
#define N_BIN_BLOCKS ((NNZ_EDGES + BIN_CHUNK - 1) / BIN_CHUNK)  // 123

// ---------- bf16 helpers (storage-only precision; accumulate in fp32) ------
__device__ __forceinline__ float gtn_bf2f(unsigned short h) {
    return __uint_as_float(((unsigned int)h) << 16);
}
__device__ __forceinline__ unsigned short gtn_f2bf(float f) {
    unsigned int u = __float_as_uint(f);
    u = u + 0x7FFFu + ((u >> 16) & 1u);      // round-to-nearest-even
    return (unsigned short)(u >> 16);
}

// ---------- CSR build, two-level bucketing ----------
// Pass 1: bin edges into 293 coarse buckets (512 rows each). LDS histogram
// per block, ONE returning global atomic per (block,bucket) (36K total vs 4M),
// LDS atomics for local rank. Edge packed as (col | inrow<<18, w_bits).
__global__ void gtn_bin_scatter_kernel(const int* __restrict__ row,
                                       const int* __restrict__ col,
                                       const float* __restrict__ w,
                                       int* __restrict__ bucketCnt,  // stride BKT_PAD
                                       int2* __restrict__ binned) {
    __shared__ int lcnt[NBKT];
    __shared__ int lbase[NBKT];
    const int chunkStart = blockIdx.x * BIN_CHUNK;
    const int chunkEnd = min(chunkStart + BIN_CHUNK, NNZ_EDGES);

    for (int b = threadIdx.x; b < NBKT; b += blockDim.x) lcnt[b] = 0;
    __syncthreads();
    for (int e = chunkStart + threadIdx.x; e < chunkEnd; e += blockDim.x)
        atomicAdd(&lcnt[row[e] >> BKT_SHIFT], 1);
    __syncthreads();
    for (int b = threadIdx.x; b < NBKT; b += blockDim.x) {
        const int c = lcnt[b];
        lbase[b] = c ? atomicAdd(&bucketCnt[b * BKT_PAD], c) : 0;
        lcnt[b] = 0;
    }
    __syncthreads();
    for (int e = chunkStart + threadIdx.x; e < chunkEnd; e += blockDim.x) {
        const int r = row[e];
        const int b = r >> BKT_SHIFT;
        const int lr = atomicAdd(&lcnt[b], 1);
        const int pos = b * BKT_CAP + lbase[b] + lr;
        binned[pos] = make_int2(col[e] | ((r & (BKT_ROWS - 1)) << 18),
                                __float_as_int(w[e]));
    }
}

// Pass 2: per-bucket row histogram -> cnt (coalesced write, no global atomics)
__global__ void gtn_bucket_hist_kernel(const int2* __restrict__ binned,
                                       const int* __restrict__ bucketCnt,
                                       int* __restrict__ cnt) {
    __shared__ int hist[BKT_ROWS];
    const int b = blockIdx.x;
    for (int t = threadIdx.x; t < BKT_ROWS; t += blockDim.x) hist[t] = 0;
    __syncthreads();
    const int n = bucketCnt[b * BKT_PAD];
    const int2* src = binned + (size_t)b * BKT_CAP;
    for (int e = threadIdx.x; e < n; e += blockDim.x)
        atomicAdd(&hist[((unsigned)src[e].x) >> 18], 1);
    __syncthreads();
    for (int t = threadIdx.x; t < BKT_ROWS; t += blockDim.x) {
        const int g = (b << BKT_SHIFT) + t;
        if (g < N_NODES) cnt[g] = hist[t];
    }
}

// block-local exclusive scan of cnt -> rowPtr, block sums -> bsum
__global__ void gtn_scan1_kernel(const int* __restrict__ cnt,
                                 int* __restrict__ rowPtr,
                                 int* __restrict__ bsum) {
    __shared__ int s[SCAN_B];
    const int i = blockIdx.x * SCAN_B + threadIdx.x;
    const int v = (i < N_NODES) ? cnt[i] : 0;
    s[threadIdx.x] = v;
    __syncthreads();
    for (int off = 1; off < SCAN_B; off <<= 1) {
        int t = (threadIdx.x >= off) ? s[threadIdx.x - off] : 0;
        __syncthreads();
        s[threadIdx.x] += t;
        __syncthreads();
    }
    if (i < N_NODES) rowPtr[i] = s[threadIdx.x] - v;   // exclusive within block
    if (threadIdx.x == SCAN_B - 1) bsum[blockIdx.x] = s[SCAN_B - 1];
}

// serial exclusive scan of 147 block sums (trivial)
__global__ void gtn_scan2_kernel(int* __restrict__ bsum) {
    int acc = 0;
    for (int i = 0; i < N_SCAN_BLOCKS; ++i) { int v = bsum[i]; bsum[i] = acc; acc += v; }
}

__global__ void gtn_scan3_kernel(int* __restrict__ rowPtr,
                                 const int* __restrict__ bsum) {
    const int i = blockIdx.x * SCAN_B + threadIdx.x;
    if (i < N_NODES) rowPtr[i] += bsum[blockIdx.x];
}

// Pass 3: place edges at final CSR positions. LDS cursors seeded from rowPtr;
// position comes from an LDS atomic. colw writes per bucket span ~113 KB -> L2.
__global__ void gtn_place_kernel(const int2* __restrict__ binned,
                                 const int* __restrict__ bucketCnt,
                                 const int* __restrict__ rowPtr,
                                 int2* __restrict__ colw) {
    __shared__ int cursor[BKT_ROWS];
    const int b = blockIdx.x;
    for (int t = threadIdx.x; t < BKT_ROWS; t += blockDim.x) {
        const int g = (b << BKT_SHIFT) + t;
        cursor[t] = (g < N_NODES) ? rowPtr[g] : 0;
    }
    __syncthreads();
    const int n = bucketCnt[b * BKT_PAD];
    const int2* src = binned + (size_t)b * BKT_CAP;
    for (int e = threadIdx.x; e < n; e += blockDim.x) {
        const int2 ed = src[e];
        const int inrow = ((unsigned)ed.x) >> 18;
        const int pos = atomicAdd(&cursor[inrow], 1);
        colw[pos] = make_int2(ed.x & 0x3FFFF, ed.y);
    }
}

// ---------- gather (16 lanes x 4 dims per edge, 4 edges/wave) ----------
// lane = grp*16 + sub. Group g handles edges 4j+g; lane holds dims
// [4*sub, 4*sub+4) as fp32 partial accumulators. Tail lanes carry (c=0,w=0)
// so the FMA is a harmless no-op against row 0 (branch-free).

// fp32 source (layer 1: reads the original split input embeddings)
__device__ __forceinline__ float4 gtn_gather_row_f32(
        int node, int lane, int sub, int grp,
        const float* __restrict__ xu, const float* __restrict__ xi,
        const int* __restrict__ rowPtr, const int* __restrict__ cnt,
        const int2* __restrict__ colw) {
    const int start = rowPtr[node];
    const int n = cnt[node];
    float4 acc = make_float4(0.f, 0.f, 0.f, 0.f);
    for (int base = 0; base < n; base += 64) {
        const int m = min(64, n - base);
        int2 e = make_int2(0, 0);
        if (lane < m) e = colw[start + base + lane];
        const int nj = (m + 3) >> 2;
        for (int j = 0; j < nj; ++j) {
            const int src = (j << 2) + grp;
            const int c = __shfl(e.x, src, 64);
            const float wv = __int_as_float(__shfl(e.y, src, 64));
            const float4* xp = (c < N_USERS)
                ? (const float4*)(xu + (size_t)c * DIM)
                : (const float4*)(xi + (size_t)(c - N_USERS) * DIM);
            const float4 xv = xp[sub];
            acc.x = fmaf(wv, xv.x, acc.x);
            acc.y = fmaf(wv, xv.y, acc.y);
            acc.z = fmaf(wv, xv.z, acc.z);
            acc.w = fmaf(wv, xv.w, acc.w);
        }
    }
    return acc;
}

// bf16 source (layers 2/3: reads the bf16 ping-pong buffer, contiguous rows)
__device__ __forceinline__ float4 gtn_gather_row_bf16(
        int node, int lane, int sub, int grp,
        const unsigned short* __restrict__ x,
        const int* __restrict__ rowPtr, const int* __restrict__ cnt,
        const int2* __restrict__ colw) {
    const int start = rowPtr[node];
    const int n = cnt[node];
    float4 acc = make_float4(0.f, 0.f, 0.f, 0.f);
    for (int base = 0; base < n; base += 64) {
        const int m = min(64, n - base);
        int2 e = make_int2(0, 0);
        if (lane < m) e = colw[start + base + lane];
        const int nj = (m + 3) >> 2;
        for (int j = 0; j < nj; ++j) {
            const int src = (j << 2) + grp;
            const int c = __shfl(e.x, src, 64);
            const float wv = __int_as_float(__shfl(e.y, src, 64));
            const ushort4 xv = *(const ushort4*)(x + (size_t)c * DIM + (sub << 2));
            acc.x = fmaf(wv, gtn_bf2f(xv.x), acc.x);
            acc.y = fmaf(wv, gtn_bf2f(xv.y), acc.y);
            acc.z = fmaf(wv, gtn_bf2f(xv.z), acc.z);
            acc.w = fmaf(wv, gtn_bf2f(xv.w), acc.w);
        }
    }
    return acc;
}

// butterfly-sum the 4 group partials; afterwards ALL lanes hold the full sum
__device__ __forceinline__ float4 gtn_reduce_groups(float4 a) {
    a.x += __shfl_xor(a.x, 16, 64);
    a.y += __shfl_xor(a.y, 16, 64);
    a.z += __shfl_xor(a.z, 16, 64);
    a.w += __shfl_xor(a.w, 16, 64);
    a.x += __shfl_xor(a.x, 32, 64);
    a.y += __shfl_xor(a.y, 32, 64);
    a.z += __shfl_xor(a.z, 32, 64);
    a.w += __shfl_xor(a.w, 32, 64);
    return a;
}

__device__ __forceinline__ void gtn_store_bf16_row(unsigned short* out,
                                                   int node, int sub, float4 o) {
    ushort4 o4;
    o4.x = gtn_f2bf(o.x);
    o4.y = gtn_f2bf(o.y);
    o4.z = gtn_f2bf(o.z);
    o4.w = gtn_f2bf(o.w);
    ((ushort4*)(out + (size_t)node * DIM))[sub] = o4;
}

// Layer 1: out(bf16) = ALPHA*x0 + BETA*gather(x0) with x0 = fp32 inputs
__global__ void gtn_layer1_kernel(const float* __restrict__ xu,
                                  const float* __restrict__ xi,
                                  const int* __restrict__ rowPtr,
                                  const int* __restrict__ cnt,
                                  const int2* __restrict__ colw,
                                  unsigned short* __restrict__ out) {
    const int lane = threadIdx.x & 63;
    const int sub = lane & 15;
    const int grp = lane >> 4;
    const int node = (blockIdx.x * blockDim.x + threadIdx.x) >> 6;
    if (node >= N_NODES) return;
    float4 agg = gtn_gather_row_f32(node, lane, sub, grp, xu, xi, rowPtr, cnt, colw);
    agg = gtn_reduce_groups(agg);
    if (grp == 0) {
        const float4 x0v = (node < N_USERS)
            ? ((const float4*)(xu + (size_t)node * DIM))[sub]
            : ((const float4*)(xi + (size_t)(node - N_USERS) * DIM))[sub];
        float4 o;
        o.x = ALPHA * x0v.x + BETA * agg.x;
        o.y = ALPHA * x0v.y + BETA * agg.y;
        o.z = ALPHA * x0v.z + BETA * agg.z;
        o.w = ALPHA * x0v.w + BETA * agg.w;
        gtn_store_bf16_row(out, node, sub, o);
    }
}

// Layer 2: out(bf16) = ALPHA*x0(fp32 inputs) + BETA*gather(bf16 buf)
__global__ void gtn_layer2_kernel(const unsigned short* __restrict__ x,
                                  const float* __restrict__ x0u,
                                  const float* __restrict__ x0i,
                                  const int* __restrict__ rowPtr,
                                  const int* __restrict__ cnt,
                                  const int2* __restrict__ colw,
                                  unsigned short* __restrict__ out) {
    const int lane = threadIdx.x & 63;
    const int sub = lane & 15;
    const int grp = lane >> 4;
    const int node = (blockIdx.x * blockDim.x + threadIdx.x) >> 6;
    if (node >= N_NODES) return;
    float4 agg = gtn_gather_row_bf16(node, lane, sub, grp, x, rowPtr, cnt, colw);
    agg = gtn_reduce_groups(agg);
    if (grp == 0) {
        const float4 x0v = (node < N_USERS)
            ? ((const float4*)(x0u + (size_t)node * DIM))[sub]
            : ((const float4*)(x0i + (size_t)(node - N_USERS) * DIM))[sub];
        float4 o;
        o.x = ALPHA * x0v.x + BETA * agg.x;
        o.y = ALPHA * x0v.y + BETA * agg.y;
        o.z = ALPHA * x0v.z + BETA * agg.z;
        o.w = ALPHA * x0v.w + BETA * agg.w;
        gtn_store_bf16_row(out, node, sub, o);
    }
}

// Fused layer-3 + dot at batch nodes only (gathers from bf16 buf)
__global__ void gtn_l3_dot_kernel(const unsigned short* __restrict__ x,
                                  const float* __restrict__ x0u,
                                  const float* __restrict__ x0i,
                                  const int* __restrict__ rowPtr,
                                  const int* __restrict__ cnt,
                                  const int2* __restrict__ colw,
                                  const int* __restrict__ users,
                                  const int* __restrict__ items,
                                  float* __restrict__ out) {
    const int lane = threadIdx.x & 63;
    const int sub = lane & 15;
    const int grp = lane >> 4;
    const int b = (blockIdx.x * blockDim.x + threadIdx.x) >> 6;
    if (b >= BATCH_SZ) return;
    const int u = users[b];
    const int it = items[b] + N_USERS;

    float4 au = gtn_gather_row_bf16(u, lane, sub, grp, x, rowPtr, cnt, colw);
    au = gtn_reduce_groups(au);
    float4 ai = gtn_gather_row_bf16(it, lane, sub, grp, x, rowPtr, cnt, colw);
    ai = gtn_reduce_groups(ai);

    const float4 x0uv = ((const float4*)(x0u + (size_t)u * DIM))[sub];
    const float4 x0iv = ((const float4*)(x0i + (size_t)(it - N_USERS) * DIM))[sub];
    float4 vu, vi;
    vu.x = ALPHA * x0uv.x + BETA * au.x;  vi.x = ALPHA * x0iv.x + BETA * ai.x;
    vu.y = ALPHA * x0uv.y + BETA * au.y;  vi.y = ALPHA * x0iv.y + BETA * ai.y;
    vu.z = ALPHA * x0uv.z + BETA * au.z;  vi.z = ALPHA * x0iv.z + BETA * ai.z;
    vu.w = ALPHA * x0uv.w + BETA * au.w;  vi.w = ALPHA * x0iv.w + BETA * ai.w;

    float p = vu.x * vi.x + vu.y * vi.y + vu.z * vi.z + vu.w * vi.w;
    p += __shfl_xor(p, 1, 64);
    p += __shfl_xor(p, 2, 64);
    p += __shfl_xor(p, 4, 64);
    p += __shfl_xor(p, 8, 64);
    if (lane == 0) out[b] = p;
}

extern "C" void kernel_launch(void* const* d_in, const int* in_sizes, int n_in,
                              void* d_out, int out_size, void* d_ws, size_t ws_size,
                              hipStream_t stream) {
    const float* user_emb  = (const float*)d_in[0];
    const float* item_emb  = (const float*)d_in[1];
    const float* edge_vals = (const float*)d_in[2];
    const int*   row       = (const int*)d_in[3];
    const int*   col       = (const int*)d_in[4];
    const int*   users     = (const int*)d_in[5];
    const int*   items     = (const int*)d_in[6];
    float* out = (float*)d_out;

    // workspace layout
    char* p = (char*)d_ws;
    unsigned short* bufA = (unsigned short*)p; p += (size_t)N_NODES * DIM * 2; // 19.2 MB
    unsigned short* bufB = (unsigned short*)p; p += (size_t)N_NODES * DIM * 2; // 19.2 MB
    int2*  colw      = (int2*)p; p += (size_t)NNZ_EDGES * sizeof(int2);        // 32 MB
    int2*  binned    = (int2*)p; p += (size_t)NBKT * BKT_CAP * sizeof(int2);   // 38.4 MB
    int*   bucketCnt = (int*)p;  p += (size_t)NBKT * BKT_PAD * sizeof(int);    // 18.75 KB
    int*   cnt       = (int*)p;  p += (size_t)N_NODES * sizeof(int);
    int*   rowPtr    = (int*)p;  p += (size_t)N_NODES * sizeof(int);
    int*   bsum      = (int*)p;  p += 256 * sizeof(int);

    const dim3 blk(256);

    // ---- CSR build (two-level bucketing) ----
    hipMemsetAsync(bucketCnt, 0, (size_t)NBKT * BKT_PAD * sizeof(int), stream);
    gtn_bin_scatter_kernel<<<dim3(N_BIN_BLOCKS), dim3(512), 0, stream>>>(
        row, col, edge_vals, bucketCnt, binned);
    gtn_bucket_hist_kernel<<<dim3(NBKT), dim3(512), 0, stream>>>(
        binned, bucketCnt, cnt);
    gtn_scan1_kernel<<<dim3(N_SCAN_BLOCKS), dim3(SCAN_B), 0, stream>>>(cnt, rowPtr, bsum);
    gtn_scan2_kernel<<<dim3(1), dim3(1), 0, stream>>>(bsum);
    gtn_scan3_kernel<<<dim3(N_SCAN_BLOCKS), dim3(SCAN_B), 0, stream>>>(rowPtr, bsum);
    gtn_place_kernel<<<dim3(NBKT), dim3(512), 0, stream>>>(
        binned, bucketCnt, rowPtr, colw);

    // ---- layers (gather, one wave per node) ----
    const dim3 layerGrid((N_NODES * 64 + 255) / 256);   // 37500 blocks
    gtn_layer1_kernel<<<layerGrid, blk, 0, stream>>>(
        user_emb, item_emb, rowPtr, cnt, colw, bufA);
    gtn_layer2_kernel<<<layerGrid, blk, 0, stream>>>(
        bufA, user_emb, item_emb, rowPtr, cnt, colw, bufB);
    const dim3 dotGrid((BATCH_SZ * 64) / 256);          // 4096 blocks
    gtn_l3_dot_kernel<<<dotGrid, blk, 0, stream>>>(
        bufB, user_emb, item_emb, rowPtr, cnt, colw, users, items, out);
}

// Round 8
// 357.205 us; speedup vs baseline: 1.5865x; 1.1084x over previous
//
#include <hip/hip_runtime.h>

#define N_USERS 100000
#define N_ITEMS 50000
#define N_NODES 150000
#define NNZ_EDGES 4000000
#define BATCH_SZ 16384
#define DIM 64
#define ALPHA 0.1f
#define BETA 0.9f          // 1 - ALPHA

#define BKT_SHIFT 9
#define BKT_ROWS  (1 << BKT_SHIFT)                        // 512 rows per bucket
#define NBKT      ((N_NODES + BKT_ROWS - 1) >> BKT_SHIFT) // 293
#define BKT_CAP   16384            // mean 13651, sigma ~117 -> 23 sigma headroom
#define BKT_PAD   16               // bucketCnt stride (64B) -> own cache line
#define BIN_CHUNK 32768            // edges per bin-scatter block
#define N_BIN_BLOCKS ((NNZ_EDGES + BIN_CHUNK - 1) / BIN_CHUNK)  // 123

// ---------- bf16 helpers (storage-only precision; accumulate in fp32) ------
__device__ __forceinline__ float gtn_bf2f(unsigned short h) {
    return __uint_as_float(((unsigned int)h) << 16);
}
__device__ __forceinline__ unsigned short gtn_f2bf(float f) {
    unsigned int u = __float_as_uint(f);
    u = u + 0x7FFFu + ((u >> 16) & 1u);      // round-to-nearest-even
    return (unsigned short)(u >> 16);
}

// x0 (fp32 split inputs) -> x0b (bf16, concatenated). Coalesced, vectorized.
__global__ void gtn_cvt_kernel(const float* __restrict__ xu,
                               const float* __restrict__ xi,
                               unsigned short* __restrict__ x0b) {
    const int total4 = N_NODES * DIM / 4;
    const int boundary4 = N_USERS * DIM / 4;
    for (int i4 = blockIdx.x * blockDim.x + threadIdx.x; i4 < total4;
         i4 += gridDim.x * blockDim.x) {
        const float4 v = (i4 < boundary4)
            ? ((const float4*)xu)[i4]
            : ((const float4*)xi)[i4 - boundary4];
        ushort4 o;
        o.x = gtn_f2bf(v.x);
        o.y = gtn_f2bf(v.y);
        o.z = gtn_f2bf(v.z);
        o.w = gtn_f2bf(v.w);
        ((ushort4*)x0b)[i4] = o;
    }
}

// ---------- CSR build, two-level bucketing ----------
// Pass 1: bin edges into 293 coarse buckets (512 rows each). LDS histogram
// per block, ONE returning global atomic per (block,bucket) (36K total vs 4M),
// LDS atomics for local rank. Edge packed as (col | inrow<<18, w_bits).
__global__ void gtn_bin_scatter_kernel(const int* __restrict__ row,
                                       const int* __restrict__ col,
                                       const float* __restrict__ w,
                                       int* __restrict__ bucketCnt,  // stride BKT_PAD
                                       int2* __restrict__ binned) {
    __shared__ int lcnt[NBKT];
    __shared__ int lbase[NBKT];
    const int chunkStart = blockIdx.x * BIN_CHUNK;
    const int chunkEnd = min(chunkStart + BIN_CHUNK, NNZ_EDGES);

    for (int b = threadIdx.x; b < NBKT; b += blockDim.x) lcnt[b] = 0;
    __syncthreads();
    for (int e = chunkStart + threadIdx.x; e < chunkEnd; e += blockDim.x)
        atomicAdd(&lcnt[row[e] >> BKT_SHIFT], 1);
    __syncthreads();
    for (int b = threadIdx.x; b < NBKT; b += blockDim.x) {
        const int c = lcnt[b];
        lbase[b] = c ? atomicAdd(&bucketCnt[b * BKT_PAD], c) : 0;
        lcnt[b] = 0;
    }
    __syncthreads();
    for (int e = chunkStart + threadIdx.x; e < chunkEnd; e += blockDim.x) {
        const int r = row[e];
        const int b = r >> BKT_SHIFT;
        const int lr = atomicAdd(&lcnt[b], 1);
        const int pos = b * BKT_CAP + lbase[b] + lr;
        binned[pos] = make_int2(col[e] | ((r & (BKT_ROWS - 1)) << 18),
                                __float_as_int(w[e]));
    }
}

// Tiny exclusive scan of the 293 bucket totals -> bktBase. One block.
__global__ void gtn_bktbase_kernel(const int* __restrict__ bucketCnt,
                                   int* __restrict__ bktBase) {
    __shared__ int s[512];
    const int t = threadIdx.x;
    const int v = (t < NBKT) ? bucketCnt[t * BKT_PAD] : 0;
    s[t] = v;
    __syncthreads();
    for (int off = 1; off < 512; off <<= 1) {
        const int tv = (t >= off) ? s[t - off] : 0;
        __syncthreads();
        s[t] += tv;
        __syncthreads();
    }
    if (t < NBKT) bktBase[t] = s[t] - v;
}

// Pass 2 (fused): per-bucket row histogram + LDS scan -> cnt/rowPtr coalesced,
// then place edges at final CSR positions via LDS cursors. One block = bucket.
__global__ void gtn_bucket_csr_kernel(const int2* __restrict__ binned,
                                      const int* __restrict__ bucketCnt,
                                      const int* __restrict__ bktBase,
                                      int* __restrict__ rowPtr,
                                      int* __restrict__ cnt,
                                      int2* __restrict__ colw) {
    __shared__ int hist[BKT_ROWS];
    __shared__ int scan[BKT_ROWS];
    __shared__ int cursor[BKT_ROWS];
    const int b = blockIdx.x;
    const int t = threadIdx.x;          // blockDim == BKT_ROWS == 512
    hist[t] = 0;
    __syncthreads();
    const int n = bucketCnt[b * BKT_PAD];
    const int2* src = binned + (size_t)b * BKT_CAP;
    for (int e = t; e < n; e += BKT_ROWS)
        atomicAdd(&hist[((unsigned)src[e].x) >> 18], 1);
    __syncthreads();
    const int v = hist[t];
    scan[t] = v;
    __syncthreads();
    for (int off = 1; off < BKT_ROWS; off <<= 1) {
        const int tv = (t >= off) ? scan[t - off] : 0;
        __syncthreads();
        scan[t] += tv;
        __syncthreads();
    }
    const int g = (b << BKT_SHIFT) + t;
    const int pos0 = bktBase[b] + scan[t] - v;   // exclusive
    if (g < N_NODES) { cnt[g] = v; rowPtr[g] = pos0; }
    cursor[t] = pos0;
    __syncthreads();
    for (int e = t; e < n; e += BKT_ROWS) {
        const int2 ed = src[e];
        const int inrow = ((unsigned)ed.x) >> 18;
        const int pos = atomicAdd(&cursor[inrow], 1);
        colw[pos] = make_int2(ed.x & 0x3FFFF, ed.y);
    }
}

// ---------- gather (16 lanes x 4 dims per edge, 4 edges/wave) ----------
// lane = grp*16 + sub. Group g handles edges 4j+g; lane holds dims
// [4*sub, 4*sub+4) as fp32 partial accumulators. Tail lanes carry (c=0,w=0)
// so the FMA is a harmless no-op against row 0 (branch-free).
__device__ __forceinline__ float4 gtn_gather_row_bf16(
        int node, int lane, int sub, int grp,
        const unsigned short* __restrict__ x,
        const int* __restrict__ rowPtr, const int* __restrict__ cnt,
        const int2* __restrict__ colw) {
    const int start = rowPtr[node];
    const int n = cnt[node];
    float4 acc = make_float4(0.f, 0.f, 0.f, 0.f);
    for (int base = 0; base < n; base += 64) {
        const int m = min(64, n - base);
        int2 e = make_int2(0, 0);
        if (lane < m) e = colw[start + base + lane];
        const int nj = (m + 3) >> 2;
        for (int j = 0; j < nj; ++j) {
            const int src = (j << 2) + grp;
            const int c = __shfl(e.x, src, 64);
            const float wv = __int_as_float(__shfl(e.y, src, 64));
            const ushort4 xv = *(const ushort4*)(x + (size_t)c * DIM + (sub << 2));
            acc.x = fmaf(wv, gtn_bf2f(xv.x), acc.x);
            acc.y = fmaf(wv, gtn_bf2f(xv.y), acc.y);
            acc.z = fmaf(wv, gtn_bf2f(xv.z), acc.z);
            acc.w = fmaf(wv, gtn_bf2f(xv.w), acc.w);
        }
    }
    return acc;
}

// butterfly-sum the 4 group partials; afterwards ALL lanes hold the full sum
__device__ __forceinline__ float4 gtn_reduce_groups(float4 a) {
    a.x += __shfl_xor(a.x, 16, 64);
    a.y += __shfl_xor(a.y, 16, 64);
    a.z += __shfl_xor(a.z, 16, 64);
    a.w += __shfl_xor(a.w, 16, 64);
    a.x += __shfl_xor(a.x, 32, 64);
    a.y += __shfl_xor(a.y, 32, 64);
    a.z += __shfl_xor(a.z, 32, 64);
    a.w += __shfl_xor(a.w, 32, 64);
    return a;
}

__device__ __forceinline__ void gtn_store_bf16_row(unsigned short* out,
                                                   int node, int sub, float4 o) {
    ushort4 o4;
    o4.x = gtn_f2bf(o.x);
    o4.y = gtn_f2bf(o.y);
    o4.z = gtn_f2bf(o.z);
    o4.w = gtn_f2bf(o.w);
    ((ushort4*)(out + (size_t)node * DIM))[sub] = o4;
}

// Layer: out(bf16) = ALPHA*x0(fp32 inputs, exact) + BETA*gather(x bf16)
__global__ void gtn_layer_kernel(const unsigned short* __restrict__ x,
                                 const float* __restrict__ x0u,
                                 const float* __restrict__ x0i,
                                 const int* __restrict__ rowPtr,
                                 const int* __restrict__ cnt,
                                 const int2* __restrict__ colw,
                                 unsigned short* __restrict__ out) {
    const int lane = threadIdx.x & 63;
    const int sub = lane & 15;
    const int grp = lane >> 4;
    const int node = (blockIdx.x * blockDim.x + threadIdx.x) >> 6;
    if (node >= N_NODES) return;
    float4 agg = gtn_gather_row_bf16(node, lane, sub, grp, x, rowPtr, cnt, colw);
    agg = gtn_reduce_groups(agg);
    if (grp == 0) {
        const float4 x0v = (node < N_USERS)
            ? ((const float4*)(x0u + (size_t)node * DIM))[sub]
            : ((const float4*)(x0i + (size_t)(node - N_USERS) * DIM))[sub];
        float4 o;
        o.x = ALPHA * x0v.x + BETA * agg.x;
        o.y = ALPHA * x0v.y + BETA * agg.y;
        o.z = ALPHA * x0v.z + BETA * agg.z;
        o.w = ALPHA * x0v.w + BETA * agg.w;
        gtn_store_bf16_row(out, node, sub, o);
    }
}

// Fused layer-3 + dot at batch nodes only (gathers from bf16 buf)
__global__ void gtn_l3_dot_kernel(const unsigned short* __restrict__ x,
                                  const float* __restrict__ x0u,
                                  const float* __restrict__ x0i,
                                  const int* __restrict__ rowPtr,
                                  const int* __restrict__ cnt,
                                  const int2* __restrict__ colw,
                                  const int* __restrict__ users,
                                  const int* __restrict__ items,
                                  float* __restrict__ out) {
    const int lane = threadIdx.x & 63;
    const int sub = lane & 15;
    const int grp = lane >> 4;
    const int b = (blockIdx.x * blockDim.x + threadIdx.x) >> 6;
    if (b >= BATCH_SZ) return;
    const int u = users[b];
    const int it = items[b] + N_USERS;

    float4 au = gtn_gather_row_bf16(u, lane, sub, grp, x, rowPtr, cnt, colw);
    au = gtn_reduce_groups(au);
    float4 ai = gtn_gather_row_bf16(it, lane, sub, grp, x, rowPtr, cnt, colw);
    ai = gtn_reduce_groups(ai);

    const float4 x0uv = ((const float4*)(x0u + (size_t)u * DIM))[sub];
    const float4 x0iv = ((const float4*)(x0i + (size_t)(it - N_USERS) * DIM))[sub];
    float4 vu, vi;
    vu.x = ALPHA * x0uv.x + BETA * au.x;  vi.x = ALPHA * x0iv.x + BETA * ai.x;
    vu.y = ALPHA * x0uv.y + BETA * au.y;  vi.y = ALPHA * x0iv.y + BETA * ai.y;
    vu.z = ALPHA * x0uv.z + BETA * au.z;  vi.z = ALPHA * x0iv.z + BETA * ai.z;
    vu.w = ALPHA * x0uv.w + BETA * au.w;  vi.w = ALPHA * x0iv.w + BETA * ai.w;

    float p = vu.x * vi.x + vu.y * vi.y + vu.z * vi.z + vu.w * vi.w;
    p += __shfl_xor(p, 1, 64);
    p += __shfl_xor(p, 2, 64);
    p += __shfl_xor(p, 4, 64);
    p += __shfl_xor(p, 8, 64);
    if (lane == 0) out[b] = p;
}

extern "C" void kernel_launch(void* const* d_in, const int* in_sizes, int n_in,
                              void* d_out, int out_size, void* d_ws, size_t ws_size,
                              hipStream_t stream) {
    const float* user_emb  = (const float*)d_in[0];
    const float* item_emb  = (const float*)d_in[1];
    const float* edge_vals = (const float*)d_in[2];
    const int*   row       = (const int*)d_in[3];
    const int*   col       = (const int*)d_in[4];
    const int*   users     = (const int*)d_in[5];
    const int*   items     = (const int*)d_in[6];
    float* out = (float*)d_out;

    // workspace layout (~129 MB)
    char* p = (char*)d_ws;
    unsigned short* x0b  = (unsigned short*)p; p += (size_t)N_NODES * DIM * 2; // 19.2 MB
    unsigned short* bufA = (unsigned short*)p; p += (size_t)N_NODES * DIM * 2; // 19.2 MB
    unsigned short* bufB = (unsigned short*)p; p += (size_t)N_NODES * DIM * 2; // 19.2 MB
    int2*  colw      = (int2*)p; p += (size_t)NNZ_EDGES * sizeof(int2);        // 32 MB
    int2*  binned    = (int2*)p; p += (size_t)NBKT * BKT_CAP * sizeof(int2);   // 38.4 MB
    int*   bucketCnt = (int*)p;  p += (size_t)NBKT * BKT_PAD * sizeof(int);    // 18.75 KB
    int*   bktBase   = (int*)p;  p += 512 * sizeof(int);
    int*   cnt       = (int*)p;  p += (size_t)N_NODES * sizeof(int);
    int*   rowPtr    = (int*)p;  p += (size_t)N_NODES * sizeof(int);

    const dim3 blk(256);

    // ---- CSR build (two-level bucketing) + x0 bf16 conversion ----
    hipMemsetAsync(bucketCnt, 0, (size_t)NBKT * BKT_PAD * sizeof(int), stream);
    gtn_bin_scatter_kernel<<<dim3(N_BIN_BLOCKS), dim3(512), 0, stream>>>(
        row, col, edge_vals, bucketCnt, binned);
    gtn_cvt_kernel<<<dim3(2048), blk, 0, stream>>>(user_emb, item_emb, x0b);
    gtn_bktbase_kernel<<<dim3(1), dim3(512), 0, stream>>>(bucketCnt, bktBase);
    gtn_bucket_csr_kernel<<<dim3(NBKT), dim3(BKT_ROWS), 0, stream>>>(
        binned, bucketCnt, bktBase, rowPtr, cnt, colw);

    // ---- layers (gather, one wave per node; all bf16 sources) ----
    const dim3 layerGrid((N_NODES * 64 + 255) / 256);   // 37500 blocks
    gtn_layer_kernel<<<layerGrid, blk, 0, stream>>>(
        x0b, user_emb, item_emb, rowPtr, cnt, colw, bufA);
    gtn_layer_kernel<<<layerGrid, blk, 0, stream>>>(
        bufA, user_emb, item_emb, rowPtr, cnt, colw, bufB);
    const dim3 dotGrid((BATCH_SZ * 64) / 256);          // 4096 blocks
    gtn_l3_dot_kernel<<<dotGrid, blk, 0, stream>>>(
        bufB, user_emb, item_emb, rowPtr, cnt, colw, users, items, out);
}

// Round 9
// 346.698 us; speedup vs baseline: 1.6346x; 1.0303x over previous
//
#include <hip/hip_runtime.h>

#define N_USERS 100000
#define N_ITEMS 50000
#define N_NODES 150000
#define NNZ_EDGES 4000000
#define BATCH_SZ 16384
#define DIM 64
#define ALPHA 0.1f
#define BETA 0.9f          // 1 - ALPHA

#define BKT_SHIFT 9
#define BKT_ROWS  (1 << BKT_SHIFT)                        // 512 rows per bucket
#define NBKT      ((N_NODES + BKT_ROWS - 1) >> BKT_SHIFT) // 293
#define BKT_CAP   16384            // mean 13651, sigma ~117 -> 23 sigma headroom
#define BKT_PAD   16               // bucketCnt stride (64B) -> own cache line
#define BIN_CHUNK 4096             // edges per bin-scatter block (R9: was 32768)
#define N_BIN_BLOCKS ((NNZ_EDGES + BIN_CHUNK - 1) / BIN_CHUNK)  // 977

// ---------- bf16 helpers (storage-only precision; accumulate in fp32) ------
__device__ __forceinline__ float gtn_bf2f(unsigned short h) {
    return __uint_as_float(((unsigned int)h) << 16);
}
__device__ __forceinline__ unsigned short gtn_f2bf(float f) {
    unsigned int u = __float_as_uint(f);
    u = u + 0x7FFFu + ((u >> 16) & 1u);      // round-to-nearest-even
    return (unsigned short)(u >> 16);
}

// x0 (fp32 split inputs) -> x0b (bf16, concatenated). Coalesced, vectorized.
__global__ void gtn_cvt_kernel(const float* __restrict__ xu,
                               const float* __restrict__ xi,
                               unsigned short* __restrict__ x0b) {
    const int total4 = N_NODES * DIM / 4;
    const int boundary4 = N_USERS * DIM / 4;
    for (int i4 = blockIdx.x * blockDim.x + threadIdx.x; i4 < total4;
         i4 += gridDim.x * blockDim.x) {
        const float4 v = (i4 < boundary4)
            ? ((const float4*)xu)[i4]
            : ((const float4*)xi)[i4 - boundary4];
        ushort4 o;
        o.x = gtn_f2bf(v.x);
        o.y = gtn_f2bf(v.y);
        o.z = gtn_f2bf(v.z);
        o.w = gtn_f2bf(v.w);
        ((ushort4*)x0b)[i4] = o;
    }
}

// ---------- CSR build, two-level bucketing ----------
// Pass 1: bin edges into 293 coarse buckets (512 rows each). LDS histogram
// per block, ONE returning global atomic per (block,bucket), LDS atomics for
// local rank. Edge packed as (col | inrow<<18, w_bits). 977 blocks for MLP.
__global__ void gtn_bin_scatter_kernel(const int* __restrict__ row,
                                       const int* __restrict__ col,
                                       const float* __restrict__ w,
                                       int* __restrict__ bucketCnt,  // stride BKT_PAD
                                       int2* __restrict__ binned) {
    __shared__ int lcnt[NBKT];
    __shared__ int lbase[NBKT];
    const int chunkStart = blockIdx.x * BIN_CHUNK;
    const int chunkEnd = min(chunkStart + BIN_CHUNK, NNZ_EDGES);

    for (int b = threadIdx.x; b < NBKT; b += blockDim.x) lcnt[b] = 0;
    __syncthreads();
    for (int e = chunkStart + threadIdx.x; e < chunkEnd; e += blockDim.x)
        atomicAdd(&lcnt[row[e] >> BKT_SHIFT], 1);
    __syncthreads();
    for (int b = threadIdx.x; b < NBKT; b += blockDim.x) {
        const int c = lcnt[b];
        lbase[b] = c ? atomicAdd(&bucketCnt[b * BKT_PAD], c) : 0;
        lcnt[b] = 0;
    }
    __syncthreads();
    for (int e = chunkStart + threadIdx.x; e < chunkEnd; e += blockDim.x) {
        const int r = row[e];
        const int b = r >> BKT_SHIFT;
        const int lr = atomicAdd(&lcnt[b], 1);
        const int pos = b * BKT_CAP + lbase[b] + lr;
        binned[pos] = make_int2(col[e] | ((r & (BKT_ROWS - 1)) << 18),
                                __float_as_int(w[e]));
    }
}

// Tiny exclusive scan of the 293 bucket totals -> bktBase. One block.
__global__ void gtn_bktbase_kernel(const int* __restrict__ bucketCnt,
                                   int* __restrict__ bktBase) {
    __shared__ int s[512];
    const int t = threadIdx.x;
    const int v = (t < NBKT) ? bucketCnt[t * BKT_PAD] : 0;
    s[t] = v;
    __syncthreads();
    for (int off = 1; off < 512; off <<= 1) {
        const int tv = (t >= off) ? s[t - off] : 0;
        __syncthreads();
        s[t] += tv;
        __syncthreads();
    }
    if (t < NBKT) bktBase[t] = s[t] - v;
}

// Pass 2 (fused): per-bucket row histogram + LDS scan -> cnt/rowPtr coalesced,
// then place edges at final CSR positions via LDS cursors. One block = bucket.
__global__ void gtn_bucket_csr_kernel(const int2* __restrict__ binned,
                                      const int* __restrict__ bucketCnt,
                                      const int* __restrict__ bktBase,
                                      int* __restrict__ rowPtr,
                                      int* __restrict__ cnt,
                                      int2* __restrict__ colw) {
    __shared__ int hist[BKT_ROWS];
    __shared__ int scan[BKT_ROWS];
    __shared__ int cursor[BKT_ROWS];
    const int b = blockIdx.x;
    const int t = threadIdx.x;          // blockDim == BKT_ROWS == 512
    hist[t] = 0;
    __syncthreads();
    const int n = bucketCnt[b * BKT_PAD];
    const int2* src = binned + (size_t)b * BKT_CAP;
    for (int e = t; e < n; e += BKT_ROWS)
        atomicAdd(&hist[((unsigned)src[e].x) >> 18], 1);
    __syncthreads();
    const int v = hist[t];
    scan[t] = v;
    __syncthreads();
    for (int off = 1; off < BKT_ROWS; off <<= 1) {
        const int tv = (t >= off) ? scan[t - off] : 0;
        __syncthreads();
        scan[t] += tv;
        __syncthreads();
    }
    const int g = (b << BKT_SHIFT) + t;
    const int pos0 = bktBase[b] + scan[t] - v;   // exclusive
    if (g < N_NODES) { cnt[g] = v; rowPtr[g] = pos0; }
    cursor[t] = pos0;
    __syncthreads();
    for (int e = t; e < n; e += BKT_ROWS) {
        const int2 ed = src[e];
        const int inrow = ((unsigned)ed.x) >> 18;
        const int pos = atomicAdd(&cursor[inrow], 1);
        colw[pos] = make_int2(ed.x & 0x3FFFF, ed.y);
    }
}

// ---------- gather (16 lanes x 4 dims per edge, 4 edges/wave) ----------
// lane = grp*16 + sub. Group g handles edges 4j+g; lane holds dims
// [4*sub, 4*sub+4) as fp32 partial accumulators. Tail lanes carry (c=0,w=0)
// so the FMA is a harmless no-op against row 0 (branch-free).
__device__ __forceinline__ float4 gtn_gather_row_bf16(
        int node, int lane, int sub, int grp,
        const unsigned short* __restrict__ x,
        const int* __restrict__ rowPtr, const int* __restrict__ cnt,
        const int2* __restrict__ colw) {
    const int start = rowPtr[node];
    const int n = cnt[node];
    float4 acc = make_float4(0.f, 0.f, 0.f, 0.f);
    for (int base = 0; base < n; base += 64) {
        const int m = min(64, n - base);
        int2 e = make_int2(0, 0);
        if (lane < m) e = colw[start + base + lane];
        const int nj = (m + 3) >> 2;
        for (int j = 0; j < nj; ++j) {
            const int src = (j << 2) + grp;
            const int c = __shfl(e.x, src, 64);
            const float wv = __int_as_float(__shfl(e.y, src, 64));
            const ushort4 xv = *(const ushort4*)(x + (size_t)c * DIM + (sub << 2));
            acc.x = fmaf(wv, gtn_bf2f(xv.x), acc.x);
            acc.y = fmaf(wv, gtn_bf2f(xv.y), acc.y);
            acc.z = fmaf(wv, gtn_bf2f(xv.z), acc.z);
            acc.w = fmaf(wv, gtn_bf2f(xv.w), acc.w);
        }
    }
    return acc;
}

// butterfly-sum the 4 group partials; afterwards ALL lanes hold the full sum
__device__ __forceinline__ float4 gtn_reduce_groups(float4 a) {
    a.x += __shfl_xor(a.x, 16, 64);
    a.y += __shfl_xor(a.y, 16, 64);
    a.z += __shfl_xor(a.z, 16, 64);
    a.w += __shfl_xor(a.w, 16, 64);
    a.x += __shfl_xor(a.x, 32, 64);
    a.y += __shfl_xor(a.y, 32, 64);
    a.z += __shfl_xor(a.z, 32, 64);
    a.w += __shfl_xor(a.w, 32, 64);
    return a;
}

__device__ __forceinline__ void gtn_store_bf16_row(unsigned short* out,
                                                   int node, int sub, float4 o) {
    ushort4 o4;
    o4.x = gtn_f2bf(o.x);
    o4.y = gtn_f2bf(o.y);
    o4.z = gtn_f2bf(o.z);
    o4.w = gtn_f2bf(o.w);
    ((ushort4*)(out + (size_t)node * DIM))[sub] = o4;
}

// Layer: out(bf16) = ALPHA*x0(fp32 inputs, exact) + BETA*gather(x bf16)
__global__ void gtn_layer_kernel(const unsigned short* __restrict__ x,
                                 const float* __restrict__ x0u,
                                 const float* __restrict__ x0i,
                                 const int* __restrict__ rowPtr,
                                 const int* __restrict__ cnt,
                                 const int2* __restrict__ colw,
                                 unsigned short* __restrict__ out) {
    const int lane = threadIdx.x & 63;
    const int sub = lane & 15;
    const int grp = lane >> 4;
    const int node = (blockIdx.x * blockDim.x + threadIdx.x) >> 6;
    if (node >= N_NODES) return;
    float4 agg = gtn_gather_row_bf16(node, lane, sub, grp, x, rowPtr, cnt, colw);
    agg = gtn_reduce_groups(agg);
    if (grp == 0) {
        const float4 x0v = (node < N_USERS)
            ? ((const float4*)(x0u + (size_t)node * DIM))[sub]
            : ((const float4*)(x0i + (size_t)(node - N_USERS) * DIM))[sub];
        float4 o;
        o.x = ALPHA * x0v.x + BETA * agg.x;
        o.y = ALPHA * x0v.y + BETA * agg.y;
        o.z = ALPHA * x0v.z + BETA * agg.z;
        o.w = ALPHA * x0v.w + BETA * agg.w;
        gtn_store_bf16_row(out, node, sub, o);
    }
}

// Fused layer-3 + dot at batch nodes only (gathers from bf16 buf)
__global__ void gtn_l3_dot_kernel(const unsigned short* __restrict__ x,
                                  const float* __restrict__ x0u,
                                  const float* __restrict__ x0i,
                                  const int* __restrict__ rowPtr,
                                  const int* __restrict__ cnt,
                                  const int2* __restrict__ colw,
                                  const int* __restrict__ users,
                                  const int* __restrict__ items,
                                  float* __restrict__ out) {
    const int lane = threadIdx.x & 63;
    const int sub = lane & 15;
    const int grp = lane >> 4;
    const int b = (blockIdx.x * blockDim.x + threadIdx.x) >> 6;
    if (b >= BATCH_SZ) return;
    const int u = users[b];
    const int it = items[b] + N_USERS;

    float4 au = gtn_gather_row_bf16(u, lane, sub, grp, x, rowPtr, cnt, colw);
    au = gtn_reduce_groups(au);
    float4 ai = gtn_gather_row_bf16(it, lane, sub, grp, x, rowPtr, cnt, colw);
    ai = gtn_reduce_groups(ai);

    const float4 x0uv = ((const float4*)(x0u + (size_t)u * DIM))[sub];
    const float4 x0iv = ((const float4*)(x0i + (size_t)(it - N_USERS) * DIM))[sub];
    float4 vu, vi;
    vu.x = ALPHA * x0uv.x + BETA * au.x;  vi.x = ALPHA * x0iv.x + BETA * ai.x;
    vu.y = ALPHA * x0uv.y + BETA * au.y;  vi.y = ALPHA * x0iv.y + BETA * ai.y;
    vu.z = ALPHA * x0uv.z + BETA * au.z;  vi.z = ALPHA * x0iv.z + BETA * ai.z;
    vu.w = ALPHA * x0uv.w + BETA * au.w;  vi.w = ALPHA * x0iv.w + BETA * ai.w;

    float p = vu.x * vi.x + vu.y * vi.y + vu.z * vi.z + vu.w * vi.w;
    p += __shfl_xor(p, 1, 64);
    p += __shfl_xor(p, 2, 64);
    p += __shfl_xor(p, 4, 64);
    p += __shfl_xor(p, 8, 64);
    if (lane == 0) out[b] = p;
}

extern "C" void kernel_launch(void* const* d_in, const int* in_sizes, int n_in,
                              void* d_out, int out_size, void* d_ws, size_t ws_size,
                              hipStream_t stream) {
    const float* user_emb  = (const float*)d_in[0];
    const float* item_emb  = (const float*)d_in[1];
    const float* edge_vals = (const float*)d_in[2];
    const int*   row       = (const int*)d_in[3];
    const int*   col       = (const int*)d_in[4];
    const int*   users     = (const int*)d_in[5];
    const int*   items     = (const int*)d_in[6];
    float* out = (float*)d_out;

    // workspace layout (~129 MB)
    char* p = (char*)d_ws;
    unsigned short* x0b  = (unsigned short*)p; p += (size_t)N_NODES * DIM * 2; // 19.2 MB
    unsigned short* bufA = (unsigned short*)p; p += (size_t)N_NODES * DIM * 2; // 19.2 MB
    unsigned short* bufB = (unsigned short*)p; p += (size_t)N_NODES * DIM * 2; // 19.2 MB
    int2*  colw      = (int2*)p; p += (size_t)NNZ_EDGES * sizeof(int2);        // 32 MB
    int2*  binned    = (int2*)p; p += (size_t)NBKT * BKT_CAP * sizeof(int2);   // 38.4 MB
    int*   bucketCnt = (int*)p;  p += (size_t)NBKT * BKT_PAD * sizeof(int);    // 18.75 KB
    int*   bktBase   = (int*)p;  p += 512 * sizeof(int);
    int*   cnt       = (int*)p;  p += (size_t)N_NODES * sizeof(int);
    int*   rowPtr    = (int*)p;  p += (size_t)N_NODES * sizeof(int);

    const dim3 blk(256);

    // ---- CSR build (two-level bucketing) + x0 bf16 conversion ----
    hipMemsetAsync(bucketCnt, 0, (size_t)NBKT * BKT_PAD * sizeof(int), stream);
    gtn_bin_scatter_kernel<<<dim3(N_BIN_BLOCKS), dim3(512), 0, stream>>>(
        row, col, edge_vals, bucketCnt, binned);
    gtn_cvt_kernel<<<dim3(2048), blk, 0, stream>>>(user_emb, item_emb, x0b);
    gtn_bktbase_kernel<<<dim3(1), dim3(512), 0, stream>>>(bucketCnt, bktBase);
    gtn_bucket_csr_kernel<<<dim3(NBKT), dim3(BKT_ROWS), 0, stream>>>(
        binned, bucketCnt, bktBase, rowPtr, cnt, colw);

    // ---- layers (gather, one wave per node; all bf16 sources) ----
    const dim3 layerGrid((N_NODES * 64 + 255) / 256);   // 37500 blocks
    gtn_layer_kernel<<<layerGrid, blk, 0, stream>>>(
        x0b, user_emb, item_emb, rowPtr, cnt, colw, bufA);
    gtn_layer_kernel<<<layerGrid, blk, 0, stream>>>(
        bufA, user_emb, item_emb, rowPtr, cnt, colw, bufB);
    const dim3 dotGrid((BATCH_SZ * 64) / 256);          // 4096 blocks
    gtn_l3_dot_kernel<<<dotGrid, blk, 0, stream>>>(
        bufB, user_emb, item_emb, rowPtr, cnt, colw, users, items, out);
}

// Round 10
// 297.389 us; speedup vs baseline: 1.9057x; 1.1658x over previous
//
#include <hip/hip_runtime.h>

#define N_USERS 100000
#define N_ITEMS 50000
#define N_NODES 150000
#define NNZ_EDGES 4000000
#define BATCH_SZ 16384
#define DIM 64
#define ALPHA 0.1f
#define BETA 0.9f          // 1 - ALPHA

#define BKT_SHIFT 9
#define BKT_ROWS  (1 << BKT_SHIFT)                        // 512 rows per bucket
#define NBKT      ((N_NODES + BKT_ROWS - 1) >> BKT_SHIFT) // 293
#define BKT_CAP   16384            // mean 13651, sigma ~117 -> 23 sigma headroom
#define BKT_PAD   16               // bucketCnt stride (64B) -> own cache line
#define BIN_CHUNK 4096             // edges per bin-scatter block
#define N_BIN_BLOCKS ((NNZ_EDGES + BIN_CHUNK - 1) / BIN_CHUNK)  // 977

// ---------- bf16 helpers (storage-only precision; accumulate in fp32) ------
__device__ __forceinline__ unsigned short gtn_f2bf(float f) {
    unsigned int u = __float_as_uint(f);
    u = u + 0x7FFFu + ((u >> 16) & 1u);      // round-to-nearest-even
    return (unsigned short)(u >> 16);
}

// x0 (fp32 split inputs) -> x0b (bf16, concatenated). Coalesced, vectorized.
__global__ void gtn_cvt_kernel(const float* __restrict__ xu,
                               const float* __restrict__ xi,
                               unsigned short* __restrict__ x0b) {
    const int total4 = N_NODES * DIM / 4;
    const int boundary4 = N_USERS * DIM / 4;
    for (int i4 = blockIdx.x * blockDim.x + threadIdx.x; i4 < total4;
         i4 += gridDim.x * blockDim.x) {
        const float4 v = (i4 < boundary4)
            ? ((const float4*)xu)[i4]
            : ((const float4*)xi)[i4 - boundary4];
        ushort4 o;
        o.x = gtn_f2bf(v.x);
        o.y = gtn_f2bf(v.y);
        o.z = gtn_f2bf(v.z);
        o.w = gtn_f2bf(v.w);
        ((ushort4*)x0b)[i4] = o;
    }
}

// ---------- CSR build, two-level bucketing ----------
__global__ void gtn_bin_scatter_kernel(const int* __restrict__ row,
                                       const int* __restrict__ col,
                                       const float* __restrict__ w,
                                       int* __restrict__ bucketCnt,  // stride BKT_PAD
                                       int2* __restrict__ binned) {
    __shared__ int lcnt[NBKT];
    __shared__ int lbase[NBKT];
    const int chunkStart = blockIdx.x * BIN_CHUNK;
    const int chunkEnd = min(chunkStart + BIN_CHUNK, NNZ_EDGES);

    for (int b = threadIdx.x; b < NBKT; b += blockDim.x) lcnt[b] = 0;
    __syncthreads();
    for (int e = chunkStart + threadIdx.x; e < chunkEnd; e += blockDim.x)
        atomicAdd(&lcnt[row[e] >> BKT_SHIFT], 1);
    __syncthreads();
    for (int b = threadIdx.x; b < NBKT; b += blockDim.x) {
        const int c = lcnt[b];
        lbase[b] = c ? atomicAdd(&bucketCnt[b * BKT_PAD], c) : 0;
        lcnt[b] = 0;
    }
    __syncthreads();
    for (int e = chunkStart + threadIdx.x; e < chunkEnd; e += blockDim.x) {
        const int r = row[e];
        const int b = r >> BKT_SHIFT;
        const int lr = atomicAdd(&lcnt[b], 1);
        const int pos = b * BKT_CAP + lbase[b] + lr;
        binned[pos] = make_int2(col[e] | ((r & (BKT_ROWS - 1)) << 18),
                                __float_as_int(w[e]));
    }
}

// Tiny exclusive scan of the 293 bucket totals -> bktBase. One block.
__global__ void gtn_bktbase_kernel(const int* __restrict__ bucketCnt,
                                   int* __restrict__ bktBase) {
    __shared__ int s[512];
    const int t = threadIdx.x;
    const int v = (t < NBKT) ? bucketCnt[t * BKT_PAD] : 0;
    s[t] = v;
    __syncthreads();
    for (int off = 1; off < 512; off <<= 1) {
        const int tv = (t >= off) ? s[t - off] : 0;
        __syncthreads();
        s[t] += tv;
        __syncthreads();
    }
    if (t < NBKT) bktBase[t] = s[t] - v;
}

// Fused: per-bucket row histogram + LDS scan -> cnt/rowPtr coalesced, then
// place edges at final CSR positions via LDS cursors. One block = bucket.
__global__ void gtn_bucket_csr_kernel(const int2* __restrict__ binned,
                                      const int* __restrict__ bucketCnt,
                                      const int* __restrict__ bktBase,
                                      int* __restrict__ rowPtr,
                                      int* __restrict__ cnt,
                                      int2* __restrict__ colw) {
    __shared__ int hist[BKT_ROWS];
    __shared__ int scan[BKT_ROWS];
    __shared__ int cursor[BKT_ROWS];
    const int b = blockIdx.x;
    const int t = threadIdx.x;          // blockDim == BKT_ROWS == 512
    hist[t] = 0;
    __syncthreads();
    const int n = bucketCnt[b * BKT_PAD];
    const int2* src = binned + (size_t)b * BKT_CAP;
    for (int e = t; e < n; e += BKT_ROWS)
        atomicAdd(&hist[((unsigned)src[e].x) >> 18], 1);
    __syncthreads();
    const int v = hist[t];
    scan[t] = v;
    __syncthreads();
    for (int off = 1; off < BKT_ROWS; off <<= 1) {
        const int tv = (t >= off) ? scan[t - off] : 0;
        __syncthreads();
        scan[t] += tv;
        __syncthreads();
    }
    const int g = (b << BKT_SHIFT) + t;
    const int pos0 = bktBase[b] + scan[t] - v;   // exclusive
    if (g < N_NODES) { cnt[g] = v; rowPtr[g] = pos0; }
    cursor[t] = pos0;
    __syncthreads();
    for (int e = t; e < n; e += BKT_ROWS) {
        const int2 ed = src[e];
        const int inrow = ((unsigned)ed.x) >> 18;
        const int pos = atomicAdd(&cursor[inrow], 1);
        colw[pos] = make_int2(ed.x & 0x3FFFF, ed.y);
    }
}

// ---------- gather (16 lanes x 4 dims per edge, 4 edges/wave) ----------
// Software-pipelined: per jb-step, issue 4 shuffle pairs + 4 INDEPENDENT
// uint2 loads (16 edges in flight per wave), then 16 FMAs. Branch-free:
// padding j slots shuffle from zeroed lanes -> c=0,w=0 -> row-0 load (L1-hit)
// + FMA with w=0. bf16 pairs unpack as <<16 / &0xFFFF0000 (elem in high half).
__device__ __forceinline__ float4 gtn_gather_row_bf16(
        int node, int lane, int sub, int grp,
        const unsigned short* __restrict__ x,
        const int* __restrict__ rowPtr, const int* __restrict__ cnt,
        const int2* __restrict__ colw) {
    const int start = rowPtr[node];
    const int n = cnt[node];
    float4 acc = make_float4(0.f, 0.f, 0.f, 0.f);
    for (int base = 0; base < n; base += 64) {
        const int m = min(64, n - base);
        int2 e = make_int2(0, 0);
        if (lane < m) e = colw[start + base + lane];
        const int nj = (m + 3) >> 2;                 // <= 16
        for (int jb = 0; jb < nj; jb += 4) {
            uint2 xv[4];
            float wv[4];
#pragma unroll
            for (int k = 0; k < 4; ++k) {
                const int src = ((jb + k) << 2) + grp;   // <= 63 always
                const int c = __shfl(e.x, src, 64);
                wv[k] = __int_as_float(__shfl(e.y, src, 64));
                xv[k] = *(const uint2*)(x + ((size_t)c << 6) + (sub << 2));
            }
#pragma unroll
            for (int k = 0; k < 4; ++k) {
                acc.x = fmaf(wv[k], __uint_as_float(xv[k].x << 16), acc.x);
                acc.y = fmaf(wv[k], __uint_as_float(xv[k].x & 0xFFFF0000u), acc.y);
                acc.z = fmaf(wv[k], __uint_as_float(xv[k].y << 16), acc.z);
                acc.w = fmaf(wv[k], __uint_as_float(xv[k].y & 0xFFFF0000u), acc.w);
            }
        }
    }
    return acc;
}

// butterfly-sum the 4 group partials; afterwards ALL lanes hold the full sum
__device__ __forceinline__ float4 gtn_reduce_groups(float4 a) {
    a.x += __shfl_xor(a.x, 16, 64);
    a.y += __shfl_xor(a.y, 16, 64);
    a.z += __shfl_xor(a.z, 16, 64);
    a.w += __shfl_xor(a.w, 16, 64);
    a.x += __shfl_xor(a.x, 32, 64);
    a.y += __shfl_xor(a.y, 32, 64);
    a.z += __shfl_xor(a.z, 32, 64);
    a.w += __shfl_xor(a.w, 32, 64);
    return a;
}

__device__ __forceinline__ void gtn_store_bf16_row(unsigned short* out,
                                                   int node, int sub, float4 o) {
    ushort4 o4;
    o4.x = gtn_f2bf(o.x);
    o4.y = gtn_f2bf(o.y);
    o4.z = gtn_f2bf(o.z);
    o4.w = gtn_f2bf(o.w);
    ((ushort4*)(out + (size_t)node * DIM))[sub] = o4;
}

// Layer: out(bf16) = ALPHA*x0(fp32 inputs, exact) + BETA*gather(x bf16)
__global__ void gtn_layer_kernel(const unsigned short* __restrict__ x,
                                 const float* __restrict__ x0u,
                                 const float* __restrict__ x0i,
                                 const int* __restrict__ rowPtr,
                                 const int* __restrict__ cnt,
                                 const int2* __restrict__ colw,
                                 unsigned short* __restrict__ out) {
    const int lane = threadIdx.x & 63;
    const int sub = lane & 15;
    const int grp = lane >> 4;
    const int node = (blockIdx.x * blockDim.x + threadIdx.x) >> 6;
    if (node >= N_NODES) return;
    float4 agg = gtn_gather_row_bf16(node, lane, sub, grp, x, rowPtr, cnt, colw);
    agg = gtn_reduce_groups(agg);
    if (grp == 0) {
        const float4 x0v = (node < N_USERS)
            ? ((const float4*)(x0u + (size_t)node * DIM))[sub]
            : ((const float4*)(x0i + (size_t)(node - N_USERS) * DIM))[sub];
        float4 o;
        o.x = ALPHA * x0v.x + BETA * agg.x;
        o.y = ALPHA * x0v.y + BETA * agg.y;
        o.z = ALPHA * x0v.z + BETA * agg.z;
        o.w = ALPHA * x0v.w + BETA * agg.w;
        gtn_store_bf16_row(out, node, sub, o);
    }
}

// Fused layer-3 + dot at batch nodes only (gathers from bf16 buf)
__global__ void gtn_l3_dot_kernel(const unsigned short* __restrict__ x,
                                  const float* __restrict__ x0u,
                                  const float* __restrict__ x0i,
                                  const int* __restrict__ rowPtr,
                                  const int* __restrict__ cnt,
                                  const int2* __restrict__ colw,
                                  const int* __restrict__ users,
                                  const int* __restrict__ items,
                                  float* __restrict__ out) {
    const int lane = threadIdx.x & 63;
    const int sub = lane & 15;
    const int grp = lane >> 4;
    const int b = (blockIdx.x * blockDim.x + threadIdx.x) >> 6;
    if (b >= BATCH_SZ) return;
    const int u = users[b];
    const int it = items[b] + N_USERS;

    float4 au = gtn_gather_row_bf16(u, lane, sub, grp, x, rowPtr, cnt, colw);
    au = gtn_reduce_groups(au);
    float4 ai = gtn_gather_row_bf16(it, lane, sub, grp, x, rowPtr, cnt, colw);
    ai = gtn_reduce_groups(ai);

    const float4 x0uv = ((const float4*)(x0u + (size_t)u * DIM))[sub];
    const float4 x0iv = ((const float4*)(x0i + (size_t)(it - N_USERS) * DIM))[sub];
    float4 vu, vi;
    vu.x = ALPHA * x0uv.x + BETA * au.x;  vi.x = ALPHA * x0iv.x + BETA * ai.x;
    vu.y = ALPHA * x0uv.y + BETA * au.y;  vi.y = ALPHA * x0iv.y + BETA * ai.y;
    vu.z = ALPHA * x0uv.z + BETA * au.z;  vi.z = ALPHA * x0iv.z + BETA * ai.z;
    vu.w = ALPHA * x0uv.w + BETA * au.w;  vi.w = ALPHA * x0iv.w + BETA * ai.w;

    float p = vu.x * vi.x + vu.y * vi.y + vu.z * vi.z + vu.w * vi.w;
    p += __shfl_xor(p, 1, 64);
    p += __shfl_xor(p, 2, 64);
    p += __shfl_xor(p, 4, 64);
    p += __shfl_xor(p, 8, 64);
    if (lane == 0) out[b] = p;
}

extern "C" void kernel_launch(void* const* d_in, const int* in_sizes, int n_in,
                              void* d_out, int out_size, void* d_ws, size_t ws_size,
                              hipStream_t stream) {
    const float* user_emb  = (const float*)d_in[0];
    const float* item_emb  = (const float*)d_in[1];
    const float* edge_vals = (const float*)d_in[2];
    const int*   row       = (const int*)d_in[3];
    const int*   col       = (const int*)d_in[4];
    const int*   users     = (const int*)d_in[5];
    const int*   items     = (const int*)d_in[6];
    float* out = (float*)d_out;

    // workspace layout (~129 MB)
    char* p = (char*)d_ws;
    unsigned short* x0b  = (unsigned short*)p; p += (size_t)N_NODES * DIM * 2; // 19.2 MB
    unsigned short* bufA = (unsigned short*)p; p += (size_t)N_NODES * DIM * 2; // 19.2 MB
    unsigned short* bufB = (unsigned short*)p; p += (size_t)N_NODES * DIM * 2; // 19.2 MB
    int2*  colw      = (int2*)p; p += (size_t)NNZ_EDGES * sizeof(int2);        // 32 MB
    int2*  binned    = (int2*)p; p += (size_t)NBKT * BKT_CAP * sizeof(int2);   // 38.4 MB
    int*   bucketCnt = (int*)p;  p += (size_t)NBKT * BKT_PAD * sizeof(int);    // 18.75 KB
    int*   bktBase   = (int*)p;  p += 512 * sizeof(int);
    int*   cnt       = (int*)p;  p += (size_t)N_NODES * sizeof(int);
    int*   rowPtr    = (int*)p;  p += (size_t)N_NODES * sizeof(int);

    const dim3 blk(256);

    // ---- CSR build (two-level bucketing) + x0 bf16 conversion ----
    hipMemsetAsync(bucketCnt, 0, (size_t)NBKT * BKT_PAD * sizeof(int), stream);
    gtn_bin_scatter_kernel<<<dim3(N_BIN_BLOCKS), dim3(512), 0, stream>>>(
        row, col, edge_vals, bucketCnt, binned);
    gtn_cvt_kernel<<<dim3(2048), blk, 0, stream>>>(user_emb, item_emb, x0b);
    gtn_bktbase_kernel<<<dim3(1), dim3(512), 0, stream>>>(bucketCnt, bktBase);
    gtn_bucket_csr_kernel<<<dim3(NBKT), dim3(BKT_ROWS), 0, stream>>>(
        binned, bucketCnt, bktBase, rowPtr, cnt, colw);

    // ---- layers (gather, one wave per node; all bf16 sources) ----
    const dim3 layerGrid((N_NODES * 64 + 255) / 256);   // 37500 blocks
    gtn_layer_kernel<<<layerGrid, blk, 0, stream>>>(
        x0b, user_emb, item_emb, rowPtr, cnt, colw, bufA);
    gtn_layer_kernel<<<layerGrid, blk, 0, stream>>>(
        bufA, user_emb, item_emb, rowPtr, cnt, colw, bufB);
    const dim3 dotGrid((BATCH_SZ * 64) / 256);          // 4096 blocks
    gtn_l3_dot_kernel<<<dotGrid, blk, 0, stream>>>(
        bufB, user_emb, item_emb, rowPtr, cnt, colw, users, items, out);
}